// Round 7
// baseline (123.952 us; speedup 1.0000x reference)
//
#include <hip/hip_runtime.h>

// ---------------------------------------------------------------------------
// BatchRelationalModule: b=16, c=64, L=256, F=64
// Round 13: KILL THE LEGACY MFMA16. MfmaUtil-implied MFMA-busy has been a
// constant ~10us across r1/r2/r3/r6 (23% x 40us), but instruction count says
// 3.2us at ubench rates => avg ~14.4 cyc/MFMA => the 16x16x16bf16_1k legacy
// op runs ~19 cyc (~4x slower than gfx950-native 16x16x32 at ~4.8). The
// gfx950 intrinsic list has ONLY the 2xK shapes; _1k is a gfx90a carryover.
// Fix: layer 2 = 2x mfma_f32_16x16x32_bf16 (K=32 over g). Layout repack
// (4 g/lane -> 8 g/lane) via 16 __shfl + 8 cndmask per iter, placed at the
// pipeline handoff so ds_bpermute latency hides under next layer-1 MFMAs.
// Layer-2 D layout unchanged => verified epilogue intact. Also
// unroll(disable) on ip-loop (i-cache hedge).
// Predict: MfmaUtil-busy 9.5 -> ~2.5us regardless; if MFMA16 was the pin,
// k_main 40 -> 26-31us, dur_us -> ~100-105. FETCH must stay ~3.2MB.
// ---------------------------------------------------------------------------

typedef short s8v __attribute__((ext_vector_type(8)));   // 8 x bf16 (4 VGPR)
typedef short s4v __attribute__((ext_vector_type(4)));   // 4 x bf16 (2 VGPR)
typedef float f4v __attribute__((ext_vector_type(4)));   // 4 x f32  (4 VGPR)
typedef int   i2v __attribute__((ext_vector_type(2)));   // 2 dwords
typedef int   i4v __attribute__((ext_vector_type(4)));   // 4 dwords

#define KEEP(x) asm volatile("" : "+v"(x))   // opaque: forbids remat/sink

#define MFMA32(a, b, c) __builtin_amdgcn_mfma_f32_16x16x32_bf16(a, b, c, 0, 0, 0)

__device__ __forceinline__ short bfr(float v) {
  return __builtin_bit_cast(short, (__bf16)v);           // fp32 -> bf16 (RNE)
}
__device__ __forceinline__ f4v relu4(f4v v) {
  f4v z = {0.f, 0.f, 0.f, 0.f};
  return __builtin_elementwise_max(v, z);
}
__device__ __forceinline__ s8v cvt8(f4v a, f4v b) {
  s8v r;
  r[0] = bfr(a[0]); r[1] = bfr(a[1]); r[2] = bfr(a[2]); r[3] = bfr(a[3]);
  r[4] = bfr(b[0]); r[5] = bfr(b[1]); r[6] = bfr(b[2]); r[7] = bfr(b[3]);
  return r;
}
__device__ __forceinline__ i2v cvt4i(f4v a) {
  s4v r;
  r[0] = bfr(a[0]); r[1] = bfr(a[1]); r[2] = bfr(a[2]); r[3] = bfr(a[3]);
  return __builtin_bit_cast(i2v, r);
}
__device__ __forceinline__ f4v ldf4(const float* p) {
  return *(const f4v*)p;
}

// Repack layer-1 output (lane: g=gt*16+quad*4+r, q=mm) into two K32
// B-operand frags (lane: q=mm, elems g=kh*32+quad*8+j).
__device__ __forceinline__ void mk_xk(const i2v pk[4], int sA, int sB,
                                      bool loq, s8v* xk0, s8v* xk1) {
  i4v w0, w1;
  int a00 = __shfl(pk[0][0], sA), a01 = __shfl(pk[1][0], sA);
  int a10 = __shfl(pk[0][1], sA), a11 = __shfl(pk[1][1], sA);
  int b00 = __shfl(pk[0][0], sB), b01 = __shfl(pk[1][0], sB);
  int b10 = __shfl(pk[0][1], sB), b11 = __shfl(pk[1][1], sB);
  w0[0] = loq ? a00 : a01;
  w0[1] = loq ? a10 : a11;
  w0[2] = loq ? b00 : b01;
  w0[3] = loq ? b10 : b11;
  int c00 = __shfl(pk[2][0], sA), c01 = __shfl(pk[3][0], sA);
  int c10 = __shfl(pk[2][1], sA), c11 = __shfl(pk[3][1], sA);
  int d00 = __shfl(pk[2][0], sB), d01 = __shfl(pk[3][0], sB);
  int d10 = __shfl(pk[2][1], sB), d11 = __shfl(pk[3][1], sB);
  w1[0] = loq ? c00 : c01;
  w1[1] = loq ? c10 : c11;
  w1[2] = loq ? d00 : d01;
  w1[3] = loq ? d10 : d11;
  *xk0 = __builtin_bit_cast(s8v, w0);
  *xk1 = __builtin_bit_cast(s8v, w1);
}

// ---------------------------------------------------------------------------
// Kernel 1: precompute A and B' (fp32). Unchanged (verified).
// ---------------------------------------------------------------------------
__global__ __launch_bounds__(256) void k_pre(
    const float* __restrict__ x, const float* __restrict__ Wg0,
    const float* __restrict__ bg0, float* __restrict__ Ag,
    float* __restrict__ Bg) {
  __shared__ float ws[64 * 131];
  __shared__ float xs[64 * 17];

  const int t = threadIdx.x;
  const int b = blockIdx.x >> 4;
  const int l0 = (blockIdx.x & 15) * 16;

  for (int i = t; i < 64 * 130; i += 256) {
    int f = i / 130, d = i - f * 130;
    ws[f * 131 + d] = Wg0[i];
  }
  for (int i = t; i < 64 * 16; i += 256) {
    int ch = i >> 4, li = i & 15;
    xs[ch * 17 + li] = x[b * 16384 + ch * 256 + l0 + li];
  }
  __syncthreads();

  const int f = t & 63;
  const int w = t >> 6;
  float accA[4] = {0.f, 0.f, 0.f, 0.f};
  float accB[4] = {0.f, 0.f, 0.f, 0.f};
  for (int d = 0; d < 64; ++d) {
    float wa = ws[f * 131 + d];
    float wb = ws[f * 131 + 65 + d];
#pragma unroll
    for (int i = 0; i < 4; ++i) {
      float xv = xs[d * 17 + w + 4 * i];
      accA[i] += xv * wa;
      accB[i] += xv * wb;
    }
  }
  const float wca = ws[f * 131 + 64];
  const float wcb = ws[f * 131 + 129];
  const float bias = bg0[f];
#pragma unroll
  for (int i = 0; i < 4; ++i) {
    int l = l0 + w + 4 * i;
    Ag[(b * 256 + l) * 64 + f] = accA[i] + (float)l * wca;
    Bg[(b * 256 + l) * 64 + f] = accB[i] + (float)l * wcb + bias;
  }
}

// ---------------------------------------------------------------------------
// Kernel 2: pair loop, all-MFMA32, software-pipelined. grid (64,16) x 256.
// Steady body: {X(ip)+layer1(ip) MFMA32s} || {layer2(xk from ip-1) MFMA32s}
// with shuffle-repack at the handoff (latency hidden under next layer1).
// launch_bounds (256,2): do NOT cap allocator (r8 lesson).
// ---------------------------------------------------------------------------
__global__ __launch_bounds__(256, 2) void k_main(
    const float* __restrict__ Ag, const float* __restrict__ Bg,
    const float* __restrict__ Wg1, const float* __restrict__ bg1,
    const float* __restrict__ Wg2, const float* __restrict__ bg2,
    float* __restrict__ Part) {
  __shared__ __align__(16) float Bs[16 * 64];   // 4 KB
  __shared__ float WaveS[4 * 64];               // 1 KB

  const int t = threadIdx.x;
  const int wid = t >> 6;
  const int lane = t & 63;
  const int mm = lane & 15;
  const int quad = lane >> 4;
  const int b = blockIdx.y;
  const int blkx = blockIdx.x;          // 0..63
  const int qq = blkx & 3;
  const int p0 = (blkx >> 2) * 16;      // 16 p-groups of 16 rows
  const int q0 = (qq * 4 + wid) * 16;

  const int sA = ((quad * 2) & 3) * 16 + mm;   // repack source lanes
  const int sB = sA + 16;
  const bool loq = quad < 2;

  // ---- stage B'[16 rows] (4 KB) into LDS, coalesced dwordx4 ----
  {
    const f4v* Bb4 = (const f4v*)(Bg + (b * 256 + p0) * 64);
    ((f4v*)Bs)[t] = Bb4[t];
  }

  // ---- A rows pinned: A[q0+mm][f = kh*32 + quad*8 + j] ----
  const float* Arow = Ag + (b * 256 + q0 + mm) * 64;
  f4v af0 = ldf4(Arow + quad * 8);
  f4v af1 = ldf4(Arow + quad * 8 + 4);
  f4v af2 = ldf4(Arow + 32 + quad * 8);
  f4v af3 = ldf4(Arow + 36 + quad * 8);

  // ---- layer-1 weights, K32 A-operand: W1[gt*16+mm][kh*32+quad*8+j] ----
  s8v W1f[4][2];
  // ---- layer-2 weights, K32 A-operand: W2[ot*16+mm][kh*32+quad*8+j] ----
  s8v W2f[4][2];
  f4v c1i[4], c2i[4];
#pragma unroll
  for (int gt = 0; gt < 4; ++gt) {
    c1i[gt] = ldf4(bg1 + gt * 16 + quad * 4);
    c2i[gt] = ldf4(bg2 + gt * 16 + quad * 4);
#pragma unroll
    for (int kh = 0; kh < 2; ++kh) {
      const float* r1 = Wg1 + (gt * 16 + mm) * 64 + kh * 32 + quad * 8;
      W1f[gt][kh] = cvt8(ldf4(r1), ldf4(r1 + 4));
      const float* r2 = Wg2 + (gt * 16 + mm) * 64 + kh * 32 + quad * 8;
      W2f[gt][kh] = cvt8(ldf4(r2), ldf4(r2 + 4));
    }
  }
  // Pin loop-invariants in registers (defeat remat/sink).
#pragma unroll
  for (int gt = 0; gt < 4; ++gt) {
    KEEP(W1f[gt][0]); KEEP(W1f[gt][1]);
    KEEP(W2f[gt][0]); KEEP(W2f[gt][1]);
    KEEP(c1i[gt]); KEEP(c2i[gt]);
  }
  KEEP(af0); KEEP(af1); KEEP(af2); KEEP(af3);

  __syncthreads();   // Bs staged

  f4v cs[4] = {{0.f,0.f,0.f,0.f},{0.f,0.f,0.f,0.f},
               {0.f,0.f,0.f,0.f},{0.f,0.f,0.f,0.f}};

  // ---- pipeline prologue: X(0) -> layer1(0) -> pk -> repack -> xk ----
  s8v xk0, xk1;
  {
    const float* bp_ = Bs;
    f4v b0 = ldf4(bp_ + quad * 8);
    f4v b1 = ldf4(bp_ + quad * 8 + 4);
    f4v b2 = ldf4(bp_ + 32 + quad * 8);
    f4v b3 = ldf4(bp_ + 36 + quad * 8);
    s8v x0 = cvt8(relu4(af0 + b0), relu4(af1 + b1));
    s8v x1 = cvt8(relu4(af2 + b2), relu4(af3 + b3));
    i2v pk[4];
#pragma unroll
    for (int gt = 0; gt < 4; ++gt) {
      f4v a1 = MFMA32(W1f[gt][1], x1, MFMA32(W1f[gt][0], x0, c1i[gt]));
      pk[gt] = cvt4i(relu4(a1));
    }
    mk_xk(pk, sA, sB, loq, &xk0, &xk1);
  }

  // ---- steady state: layer1(ip) || layer2(ip-1) ----
#pragma clang loop unroll(disable)
  for (int ip = 1; ip < 16; ++ip) {
    // stream A: next p
    const float* bp_ = Bs + ip * 64;
    f4v b0 = ldf4(bp_ + quad * 8);
    f4v b1 = ldf4(bp_ + quad * 8 + 4);
    f4v b2 = ldf4(bp_ + 32 + quad * 8);
    f4v b3 = ldf4(bp_ + 36 + quad * 8);
    s8v x0 = cvt8(relu4(af0 + b0), relu4(af1 + b1));
    s8v x1 = cvt8(relu4(af2 + b2), relu4(af3 + b3));
    f4v a1[4];
#pragma unroll
    for (int gt = 0; gt < 4; ++gt)
      a1[gt] = MFMA32(W1f[gt][1], x1, MFMA32(W1f[gt][0], x0, c1i[gt]));

    // stream B: previous p's layer 2 (all MFMA32, independent of stream A)
#pragma unroll
    for (int ot = 0; ot < 4; ++ot) {
      f4v a2 = MFMA32(W2f[ot][1], xk1, MFMA32(W2f[ot][0], xk0, c2i[ot]));
      cs[ot] += relu4(a2);   // lane: o = ot*16+quad*4+r, q = mm
    }

    // handoff: pk -> repack -> xk (shuffle latency hides under next layer1)
    i2v pk[4];
#pragma unroll
    for (int gt = 0; gt < 4; ++gt) pk[gt] = cvt4i(relu4(a1[gt]));
    mk_xk(pk, sA, sB, loq, &xk0, &xk1);
  }

  // ---- pipeline epilogue: layer2 on last xk ----
#pragma unroll
  for (int ot = 0; ot < 4; ++ot) {
    f4v a2 = MFMA32(W2f[ot][1], xk1, MFMA32(W2f[ot][0], xk0, c2i[ot]));
    cs[ot] += relu4(a2);
  }

  // ---- reduce over q (mm lanes) -> per-wave LDS slice (NO atomics) ----
#pragma unroll
  for (int ot = 0; ot < 4; ++ot) {
#pragma unroll
    for (int r = 0; r < 4; ++r) {
      float v = cs[ot][r];
      v += __shfl_xor(v, 1);
      v += __shfl_xor(v, 2);
      v += __shfl_xor(v, 4);
      v += __shfl_xor(v, 8);
      if (mm == 0) WaveS[wid * 64 + ot * 16 + quad * 4 + r] = v;
    }
  }
  __syncthreads();
  if (t < 64) {
    float s = WaveS[t] + WaveS[64 + t] + WaveS[128 + t] + WaveS[192 + t];
    Part[(b * 64 + blkx) * 64 + t] = s;   // distinct slot, no contention
  }
}

// ---------------------------------------------------------------------------
// Kernel 3: reduce 64 partials per (b,o), then f-network. grid 16 x 256.
// ---------------------------------------------------------------------------
__global__ __launch_bounds__(256) void k_final(
    const float* __restrict__ Part, const float* __restrict__ Wp,
    const float* __restrict__ bp, const float* __restrict__ Wo,
    const float* __restrict__ bo, float* __restrict__ out) {
  __shared__ float red[4][64];
  __shared__ float sv[64], tv[64];
  const int b = blockIdx.x, t = threadIdx.x;
  const int o = t & 63, jw = t >> 6;
  const float* Pb = Part + b * 64 * 64;
  float s = 0.f;
#pragma unroll
  for (int j = 0; j < 16; ++j) s += Pb[(jw * 16 + j) * 64 + o];  // coalesced
  red[jw][o] = s;
  __syncthreads();
  if (t < 64) sv[t] = red[0][t] + red[1][t] + red[2][t] + red[3][t];
  __syncthreads();
  if (t < 64) {
    float acc = bp[t];
#pragma unroll
    for (int g4 = 0; g4 < 16; ++g4) {
      f4v wv = ldf4(Wp + t * 64 + g4 * 4);
      f4v xv = ldf4(sv + g4 * 4);
      acc += wv[0] * xv[0] + wv[1] * xv[1] + wv[2] * xv[2] + wv[3] * xv[3];
    }
    tv[t] = fmaxf(acc, 0.f);
  }
  __syncthreads();
  if (t < 64) {
    float o2 = bo[t];
#pragma unroll
    for (int g4 = 0; g4 < 16; ++g4) {
      f4v wv = ldf4(Wo + t * 64 + g4 * 4);
      f4v xv = ldf4(tv + g4 * 4);
      o2 += wv[0] * xv[0] + wv[1] * xv[1] + wv[2] * xv[2] + wv[3] * xv[3];
    }
    out[b * 64 + t] = o2;
  }
}

// ---------------------------------------------------------------------------
extern "C" void kernel_launch(void* const* d_in, const int* in_sizes, int n_in,
                              void* d_out, int out_size, void* d_ws, size_t ws_size,
                              hipStream_t stream) {
  const float* x   = (const float*)d_in[0];
  const float* Wg0 = (const float*)d_in[1];
  const float* bg0 = (const float*)d_in[2];
  const float* Wg1 = (const float*)d_in[3];
  const float* bg1 = (const float*)d_in[4];
  const float* Wg2 = (const float*)d_in[5];
  const float* bg2 = (const float*)d_in[6];
  const float* Wp  = (const float*)d_in[7];
  const float* bp  = (const float*)d_in[8];
  const float* Wo  = (const float*)d_in[9];
  const float* bo  = (const float*)d_in[10];
  float* out = (float*)d_out;

  float* Ag   = (float*)d_ws;            // [16][256][64] fp32 = 1 MB
  float* Bg   = Ag + 16 * 256 * 64;      // [16][256][64] fp32 = 1 MB
  float* Part = Bg + 16 * 256 * 64;      // [16][64][64] fp32 = 256 KB

  k_pre<<<256, 256, 0, stream>>>(x, Wg0, bg0, Ag, Bg);
  k_main<<<dim3(64, 16), 256, 0, stream>>>(Ag, Bg, Wg1, bg1, Wg2, bg2, Part);
  k_final<<<16, 256, 0, stream>>>(Part, Wp, bp, Wo, bo, out);
}

// Round 8
// 123.070 us; speedup vs baseline: 1.0072x; 1.0072x over previous
//
#include <hip/hip_runtime.h>

// ---------------------------------------------------------------------------
// BatchRelationalModule: b=16, c=64, L=256, F=64
// Round 14: DUAL-p CHAINS, SLIMMED (r10 retry minus the baggage).
// r13 falsified the slow-MFMA16 theory: per-MFMA pipe-busy is ~14.4cyc for
// BOTH shapes (r6: 9.2us/1.57M, r7: 6.2us/1.05M); the shfl repack added 2.1M
// bank-conflict cycles on the critical path => reverted (back to MFMA16
// chains, no repack). 7-round pattern: k_main time ~ total work, insensitive
// to occupancy/memory-path/MFMA-shape/1-deep pipeline; ~1500cyc/iter vs
// ~350cyc issue => serial-wave latency exposure. Untested lever: two
// independent p-chains per wave SHARING af/cs/weights (r10 crashed; this
// version drops per-chain rotation + manual interleave, uses
// launch_bounds(256,1) for 512-VGPR headroom, unroll(disable), 32p/block
// (r0 geometry, 2x prologue amortization).
// Predict: VGPR 180-230, FETCH ~3.3MB, conflicts ~0, k_main 40 -> 26-31us,
// dur_us -> 103-108. Crash => dual-chain codegen broken, consolidate r6.
// ---------------------------------------------------------------------------

typedef short s8v __attribute__((ext_vector_type(8)));   // 8 x bf16 (4 VGPR)
typedef short s4v __attribute__((ext_vector_type(4)));   // 4 x bf16 (2 VGPR)
typedef float f4v __attribute__((ext_vector_type(4)));   // 4 x f32  (4 VGPR)

#define KEEP(x) asm volatile("" : "+v"(x))   // opaque: forbids remat/sink

#define MFMA16(a, b, c) __builtin_amdgcn_mfma_f32_16x16x16bf16_1k(a, b, c, 0, 0, 0)
#define MFMA32(a, b, c) __builtin_amdgcn_mfma_f32_16x16x32_bf16(a, b, c, 0, 0, 0)

__device__ __forceinline__ short bfr(float v) {
  return __builtin_bit_cast(short, (__bf16)v);           // fp32 -> bf16 (RNE)
}
__device__ __forceinline__ f4v relu4(f4v v) {
  f4v z = {0.f, 0.f, 0.f, 0.f};
  return __builtin_elementwise_max(v, z);
}
__device__ __forceinline__ s8v cvt8(f4v a, f4v b) {
  s8v r;
  r[0] = bfr(a[0]); r[1] = bfr(a[1]); r[2] = bfr(a[2]); r[3] = bfr(a[3]);
  r[4] = bfr(b[0]); r[5] = bfr(b[1]); r[6] = bfr(b[2]); r[7] = bfr(b[3]);
  return r;
}
__device__ __forceinline__ s4v cvt4(f4v a) {
  s4v r;
  r[0] = bfr(a[0]); r[1] = bfr(a[1]); r[2] = bfr(a[2]); r[3] = bfr(a[3]);
  return r;
}
__device__ __forceinline__ f4v ldf4(const float* p) {
  return *(const f4v*)p;
}

// ---------------------------------------------------------------------------
// Kernel 1: precompute A and B' (fp32). Unchanged (verified).
// ---------------------------------------------------------------------------
__global__ __launch_bounds__(256) void k_pre(
    const float* __restrict__ x, const float* __restrict__ Wg0,
    const float* __restrict__ bg0, float* __restrict__ Ag,
    float* __restrict__ Bg) {
  __shared__ float ws[64 * 131];
  __shared__ float xs[64 * 17];

  const int t = threadIdx.x;
  const int b = blockIdx.x >> 4;
  const int l0 = (blockIdx.x & 15) * 16;

  for (int i = t; i < 64 * 130; i += 256) {
    int f = i / 130, d = i - f * 130;
    ws[f * 131 + d] = Wg0[i];
  }
  for (int i = t; i < 64 * 16; i += 256) {
    int ch = i >> 4, li = i & 15;
    xs[ch * 17 + li] = x[b * 16384 + ch * 256 + l0 + li];
  }
  __syncthreads();

  const int f = t & 63;
  const int w = t >> 6;
  float accA[4] = {0.f, 0.f, 0.f, 0.f};
  float accB[4] = {0.f, 0.f, 0.f, 0.f};
  for (int d = 0; d < 64; ++d) {
    float wa = ws[f * 131 + d];
    float wb = ws[f * 131 + 65 + d];
#pragma unroll
    for (int i = 0; i < 4; ++i) {
      float xv = xs[d * 17 + w + 4 * i];
      accA[i] += xv * wa;
      accB[i] += xv * wb;
    }
  }
  const float wca = ws[f * 131 + 64];
  const float wcb = ws[f * 131 + 129];
  const float bias = bg0[f];
#pragma unroll
  for (int i = 0; i < 4; ++i) {
    int l = l0 + w + 4 * i;
    Ag[(b * 256 + l) * 64 + f] = accA[i] + (float)l * wca;
    Bg[(b * 256 + l) * 64 + f] = accB[i] + (float)l * wcb + bias;
  }
}

// ---------------------------------------------------------------------------
// Kernel 2: pair loop, dual-p chains. grid (32, 16) x 256 thr (r0 geometry:
// 32 p-rows/block, 4 waves x 16q). Loop: 16 dual-iterations; chains share
// af (A-frags), cs (accumulators), W1f/W2f/c1i/c2i (weights); only B-frags,
// X-frags, layer accs are per-chain (transient). launch_bounds(256,1):
// allocator headroom to 512 VGPR (residency pinned ~1.4 blocks anyway; the
// r8 spill disaster came from capping, not relaxing).
// ---------------------------------------------------------------------------
__global__ __launch_bounds__(256, 1) void k_main(
    const float* __restrict__ Ag, const float* __restrict__ Bg,
    const float* __restrict__ Wg1, const float* __restrict__ bg1,
    const float* __restrict__ Wg2, const float* __restrict__ bg2,
    float* __restrict__ Part) {
  __shared__ __align__(16) float Bs[32 * 64];   // 8 KB
  __shared__ float WaveS[4 * 64];               // 1 KB

  const int t = threadIdx.x;
  const int wid = t >> 6;
  const int lane = t & 63;
  const int mm = lane & 15;
  const int quad = lane >> 4;
  const int b = blockIdx.y;
  const int blkx = blockIdx.x;          // 0..31
  const int qq = blkx & 3;
  const int p0 = (blkx >> 2) * 32;      // 8 p-groups of 32 rows
  const int q0 = (qq * 4 + wid) * 16;

  // ---- stage B'[32 rows] (8 KB) into LDS, coalesced dwordx4 ----
  {
    const f4v* Bb4 = (const f4v*)(Bg + (b * 256 + p0) * 64);
    ((f4v*)Bs)[t] = Bb4[t];
    ((f4v*)Bs)[t + 256] = Bb4[t + 256];
  }

  // ---- A rows pinned: A[q0+mm][f = kh*32 + quad*8 + j] ----
  const float* Arow = Ag + (b * 256 + q0 + mm) * 64;
  f4v af0 = ldf4(Arow + quad * 8);
  f4v af1 = ldf4(Arow + quad * 8 + 4);
  f4v af2 = ldf4(Arow + 32 + quad * 8);
  f4v af3 = ldf4(Arow + 36 + quad * 8);

  // ---- layer-1 weights, K32 A-operand: W1[gt*16+mm][kh*32+quad*8+j] ----
  s8v W1f[4][2];
  // ---- layer-2 weights, K16 A-operand: W2[ot*16+mm][gt*16+quad*4+i] ----
  s4v W2f[4][4];
  f4v c1i[4], c2i[4];
#pragma unroll
  for (int gt = 0; gt < 4; ++gt) {
    c1i[gt] = ldf4(bg1 + gt * 16 + quad * 4);
    c2i[gt] = ldf4(bg2 + gt * 16 + quad * 4);
#pragma unroll
    for (int kh = 0; kh < 2; ++kh) {
      const float* r1 = Wg1 + (gt * 16 + mm) * 64 + kh * 32 + quad * 8;
      W1f[gt][kh] = cvt8(ldf4(r1), ldf4(r1 + 4));
    }
#pragma unroll
    for (int kt = 0; kt < 4; ++kt) {
      const float* r2 = Wg2 + (gt * 16 + mm) * 64 + kt * 16 + quad * 4;
      W2f[gt][kt] = cvt4(ldf4(r2));
    }
  }
  // Pin loop-invariant weights/biases (defeat remat/sink) — r6-proven set.
#pragma unroll
  for (int gt = 0; gt < 4; ++gt) {
    KEEP(W1f[gt][0]); KEEP(W1f[gt][1]);
    KEEP(W2f[gt][0]); KEEP(W2f[gt][1]); KEEP(W2f[gt][2]); KEEP(W2f[gt][3]);
    KEEP(c1i[gt]); KEEP(c2i[gt]);
  }
  KEEP(af0); KEEP(af1); KEEP(af2); KEEP(af3);

  __syncthreads();   // Bs staged

  f4v cs[4] = {{0.f,0.f,0.f,0.f},{0.f,0.f,0.f,0.f},
               {0.f,0.f,0.f,0.f},{0.f,0.f,0.f,0.f}};

#pragma clang loop unroll(disable)
  for (int ip = 0; ip < 32; ip += 2) {
    // ---- chain A = row ip, chain B = row ip+1 (B-frags die after X) ----
    const float* bA = Bs + ip * 64;
    const float* bB = bA + 64;
    s8v xA0, xA1, xB0, xB1;
    {
      f4v a0 = ldf4(bA + quad * 8);
      f4v a1_ = ldf4(bA + quad * 8 + 4);
      f4v a2_ = ldf4(bA + 32 + quad * 8);
      f4v a3_ = ldf4(bA + 36 + quad * 8);
      xA0 = cvt8(relu4(af0 + a0), relu4(af1 + a1_));
      xA1 = cvt8(relu4(af2 + a2_), relu4(af3 + a3_));
      f4v b0 = ldf4(bB + quad * 8);
      f4v b1_ = ldf4(bB + quad * 8 + 4);
      f4v b2_ = ldf4(bB + 32 + quad * 8);
      f4v b3_ = ldf4(bB + 36 + quad * 8);
      xB0 = cvt8(relu4(af0 + b0), relu4(af1 + b1_));
      xB1 = cvt8(relu4(af2 + b2_), relu4(af3 + b3_));
    }

    // ---- layer 1: two independent chain sets (compiler interleaves) ----
    f4v a1A[4], a1B[4];
#pragma unroll
    for (int gt = 0; gt < 4; ++gt)
      a1A[gt] = MFMA32(W1f[gt][1], xA1, MFMA32(W1f[gt][0], xA0, c1i[gt]));
#pragma unroll
    for (int gt = 0; gt < 4; ++gt)
      a1B[gt] = MFMA32(W1f[gt][1], xB1, MFMA32(W1f[gt][0], xB0, c1i[gt]));

    s4v pkA[4], pkB[4];
#pragma unroll
    for (int gt = 0; gt < 4; ++gt) pkA[gt] = cvt4(relu4(a1A[gt]));
#pragma unroll
    for (int gt = 0; gt < 4; ++gt) pkB[gt] = cvt4(relu4(a1B[gt]));

    // ---- layer 2: 8 independent MFMA16 chains, shared cs accumulate ----
#pragma unroll
    for (int ot = 0; ot < 4; ++ot) {
      f4v aA = MFMA16(W2f[ot][3], pkA[3],
               MFMA16(W2f[ot][2], pkA[2],
               MFMA16(W2f[ot][1], pkA[1],
               MFMA16(W2f[ot][0], pkA[0], c2i[ot]))));
      f4v aB = MFMA16(W2f[ot][3], pkB[3],
               MFMA16(W2f[ot][2], pkB[2],
               MFMA16(W2f[ot][1], pkB[1],
               MFMA16(W2f[ot][0], pkB[0], c2i[ot]))));
      cs[ot] += relu4(aA) + relu4(aB);   // lane: o = ot*16+quad*4+r, q = mm
    }
  }

  // ---- reduce over q (mm lanes) -> per-wave LDS slice (NO atomics) ----
#pragma unroll
  for (int ot = 0; ot < 4; ++ot) {
#pragma unroll
    for (int r = 0; r < 4; ++r) {
      float v = cs[ot][r];
      v += __shfl_xor(v, 1);
      v += __shfl_xor(v, 2);
      v += __shfl_xor(v, 4);
      v += __shfl_xor(v, 8);
      if (mm == 0) WaveS[wid * 64 + ot * 16 + quad * 4 + r] = v;
    }
  }
  __syncthreads();
  if (t < 64) {
    float s = WaveS[t] + WaveS[64 + t] + WaveS[128 + t] + WaveS[192 + t];
    Part[(b * 32 + blkx) * 64 + t] = s;   // distinct slot, no contention
  }
}

// ---------------------------------------------------------------------------
// Kernel 3: reduce 32 partials per (b,o), then f-network. grid 16 x 256.
// ---------------------------------------------------------------------------
__global__ __launch_bounds__(256) void k_final(
    const float* __restrict__ Part, const float* __restrict__ Wp,
    const float* __restrict__ bp, const float* __restrict__ Wo,
    const float* __restrict__ bo, float* __restrict__ out) {
  __shared__ float red[4][64];
  __shared__ float sv[64], tv[64];
  const int b = blockIdx.x, t = threadIdx.x;
  const int o = t & 63, jw = t >> 6;
  const float* Pb = Part + b * 32 * 64;
  float s = 0.f;
#pragma unroll
  for (int j = 0; j < 8; ++j) s += Pb[(jw * 8 + j) * 64 + o];  // coalesced
  red[jw][o] = s;
  __syncthreads();
  if (t < 64) sv[t] = red[0][t] + red[1][t] + red[2][t] + red[3][t];
  __syncthreads();
  if (t < 64) {
    float acc = bp[t];
#pragma unroll
    for (int g4 = 0; g4 < 16; ++g4) {
      f4v wv = ldf4(Wp + t * 64 + g4 * 4);
      f4v xv = ldf4(sv + g4 * 4);
      acc += wv[0] * xv[0] + wv[1] * xv[1] + wv[2] * xv[2] + wv[3] * xv[3];
    }
    tv[t] = fmaxf(acc, 0.f);
  }
  __syncthreads();
  if (t < 64) {
    float o2 = bo[t];
#pragma unroll
    for (int g4 = 0; g4 < 16; ++g4) {
      f4v wv = ldf4(Wo + t * 64 + g4 * 4);
      f4v xv = ldf4(tv + g4 * 4);
      o2 += wv[0] * xv[0] + wv[1] * xv[1] + wv[2] * xv[2] + wv[3] * xv[3];
    }
    out[b * 64 + t] = o2;
  }
}

// ---------------------------------------------------------------------------
extern "C" void kernel_launch(void* const* d_in, const int* in_sizes, int n_in,
                              void* d_out, int out_size, void* d_ws, size_t ws_size,
                              hipStream_t stream) {
  const float* x   = (const float*)d_in[0];
  const float* Wg0 = (const float*)d_in[1];
  const float* bg0 = (const float*)d_in[2];
  const float* Wg1 = (const float*)d_in[3];
  const float* bg1 = (const float*)d_in[4];
  const float* Wg2 = (const float*)d_in[5];
  const float* bg2 = (const float*)d_in[6];
  const float* Wp  = (const float*)d_in[7];
  const float* bp  = (const float*)d_in[8];
  const float* Wo  = (const float*)d_in[9];
  const float* bo  = (const float*)d_in[10];
  float* out = (float*)d_out;

  float* Ag   = (float*)d_ws;            // [16][256][64] fp32 = 1 MB
  float* Bg   = Ag + 16 * 256 * 64;      // [16][256][64] fp32 = 1 MB
  float* Part = Bg + 16 * 256 * 64;      // [16][32][64] fp32 = 128 KB

  k_pre<<<256, 256, 0, stream>>>(x, Wg0, bg0, Ag, Bg);
  k_main<<<dim3(32, 16), 256, 0, stream>>>(Ag, Bg, Wg1, bg1, Wg2, bg2, Part);
  k_final<<<16, 256, 0, stream>>>(Part, Wp, bp, Wo, bo, out);
}